// Round 3
// baseline (373.818 us; speedup 1.0000x reference)
//
#include <hip/hip_runtime.h>

// Stencil gather: out[b,j,k,{center,up,right,down,left}], edge-replicated.
// B=16, H=1024, W=1024, f32. Memory-bound: 64 MiB read + 320 MiB write
// -> ~61 us floor at 6.3 TB/s.
//
// R1 lesson: per-thread 80B-contiguous stores are lane-strided within each
// store instruction -> ~4x store-line amplification -> kernel ~204 us.
// R2 lesson: LDS staging + coalesced 1KB/instr stores with NONTEMPORAL flag
// -> kernel ~140 us. nt bypasses L2 write combining (evict-first/no-alloc),
// pushing 16x64B raw transactions per wave store at ~50% HBM efficiency.
// R3: plain stores -- let L2 absorb and stream full lines (the harness's own
// fill kernel sustains 6.5 TB/s on this same buffer with normal stores).
//
// Mapping: 1 block (256 threads) = 1 image row = 1024 pixels = 20 KiB output.
//  Phase 1: thread i computes pixels [4i,4i+4) -> 5 float4s -> LDS at 80B*i.
//  Phase 2: barrier; thread i stores LDS float4 [i+256r] -> out float4
//           [block_base + i + 256r], r=0..4. Fully coalesced.

typedef float f4 __attribute__((ext_vector_type(4)));

__global__ __launch_bounds__(256) void stencil5_kernel(
    const float* __restrict__ in, float* __restrict__ out) {
    constexpr int W = 1024;
    constexpr int H = 1024;

    __shared__ float lds[256 * 20];   // 20 KiB

    const int i   = threadIdx.x;
    const int row = blockIdx.x;        // global row in [0, B*H)
    const int k0  = i << 2;            // starting column (multiple of 4)
    const int j   = row & (H - 1);     // row within image

    const long base = ((long)row << 10);
    const float* prow = in + base + k0;

    // Center (16B-aligned).
    const float4 c = *(const float4*)prow;

    // Up / down rows, replicating the center row at borders (wave-uniform).
    const float* uptr = prow - ((j > 0)     ? W : 0);
    const float* dptr = prow + ((j < H - 1) ? W : 0);
    const float4 u = *(const float4*)uptr;
    const float4 d = *(const float4*)dptr;

    // Left neighbor of pixel0 / right neighbor of pixel3 (clamped address,
    // then per-lane select to center at the image border).
    float lx = prow[-(k0 > 0 ? 1 : 0)];
    lx = (k0 > 0) ? lx : c.x;
    float rw = prow[(k0 + 4 < W) ? 4 : 3];
    rw = (k0 + 4 < W) ? rw : c.w;

    // Per-pixel output (pixel-major, channel-minor), 20 floats:
    // [c.x,u.x,c.y,d.x,lx | c.y,u.y,c.z,d.y,c.x | c.z,u.z,c.w,d.z,c.y |
    //  c.w,u.w,rw,d.w,c.z]
    float4* l = (float4*)(lds + i * 20);
    l[0] = make_float4(c.x, u.x, c.y, d.x);
    l[1] = make_float4(lx,  c.y, u.y, c.z);
    l[2] = make_float4(d.y, c.x, c.z, u.z);
    l[3] = make_float4(c.w, d.z, c.y, c.w);
    l[4] = make_float4(u.w, rw,  d.w, c.z);

    __syncthreads();

    // Coalesced streaming store of the block's 20 KiB (1280 float4s).
    const f4* ls = (const f4*)lds;
    f4* o = (f4*)(out + base * 5);
    #pragma unroll
    for (int r = 0; r < 5; ++r) {
        o[i + 256 * r] = ls[i + 256 * r];
    }
}

extern "C" void kernel_launch(void* const* d_in, const int* in_sizes, int n_in,
                              void* d_out, int out_size, void* d_ws, size_t ws_size,
                              hipStream_t stream) {
    const float* in = (const float*)d_in[0];
    float* out = (float*)d_out;

    const int n = in_sizes[0];       // B*H*W = 16 * 1024 * 1024
    const int blocks = n >> 10;      // one block per 1024-pixel row = 16384

    stencil5_kernel<<<blocks, 256, 0, stream>>>(in, out);
}